// Round 1
// baseline (190.055 us; speedup 1.0000x reference)
//
#include <hip/hip_runtime.h>
#include <hip/hip_bf16.h>

#define N_NODES 50000
#define N_EDGES 800000
#define DIM 64
#define NHEAD 2
#define HD 128     // NHEAD * DIM
#define NCOL 448   // 128 q + 128 k + 128 vc + 64 skipc
#define MAXDEG 64  // ELL row stride; max Poisson(16) deg over 50k nodes ~ 45

#define NBIN 196    // bins of 256 nodes: 196*256 = 50176 >= 50000
#define BCAP 6144   // bin capacity; lambda=4082, +32 sigma
#define ACH 2048    // edges per bin-block (2048 -> 21KB LDS, ~4 blocks/CU)
#define BIN_BLKS 391 // ceil(800000/2048)

#define PREP_B 112  // 448*64/256
#define PROJ_B 782  // ceil(50000/64)

// q pre-scale: 1/sqrt(64) * 1/ln(2)  -> logits are in exp2 domain
#define QSCALE 0.18033688011112042f

typedef short bf16x8 __attribute__((ext_vector_type(8)));
typedef float f32x16 __attribute__((ext_vector_type(16)));
typedef float f32x2 __attribute__((ext_vector_type(2)));

__device__ __forceinline__ unsigned short f2bf(float f) {
    unsigned u = __float_as_uint(f);
    unsigned r = (u + 0x7fffu + ((u >> 16) & 1u)) >> 16;   // RNE
    return (unsigned short)r;
}
// fp8 e4m3 HW converts (gfx950 OCP): encode f32 -> 1 byte
__device__ __forceinline__ unsigned char f2fp8(float f) {
    int r = __builtin_amdgcn_cvt_pk_fp8_f32(f, f, 0, false);
    return (unsigned char)(r & 0xff);
}

// ------- merged: folded-weight prep ∥ edge binning (bincnt pre-zeroed by memset) -------
__global__ __launch_bounds__(256) void k_pb(
    const int* __restrict__ ei,
    const float* __restrict__ Wq, const float* __restrict__ bq,
    const float* __restrict__ Wk, const float* __restrict__ bk,
    const float* __restrict__ Wv, const float* __restrict__ bv,
    const float* __restrict__ Wskip, const float* __restrict__ bskip,
    const float* __restrict__ Wc, const float* __restrict__ bc,
    unsigned short* __restrict__ WallT, float* __restrict__ ball,
    int* __restrict__ bincnt, unsigned* __restrict__ bins,
    double* __restrict__ stats)
{
    const int t = threadIdx.x;
    if (blockIdx.x < PREP_B) {
        int gid = blockIdx.x * 256 + t;   // 0..28671
        if (gid == 0) { stats[0] = 0.0; stats[1] = 0.0; }
        const int j = gid >> 6;   // output column 0..447
        const int d = gid & 63;   // k index
        float w, bb;
        if (j < 128) {
            w = Wq[d * HD + j] * QSCALE;
            bb = bq[j] * QSCALE;
        } else if (j < 256) {
            int jj = j - 128;
            w = Wk[d * HD + jj];
            bb = bk[jj];
        } else if (j < 384) {
            int jj = j - 256;
            int h = jj >> 6, jc = jj & 63;
            float s = 0.f, sb = 0.f;
            for (int c = 0; c < 64; c++) {
                float wc = Wc[(h * 64 + c) * DIM + jc];
                s  += Wv[d * HD + h * 64 + c] * wc;
                sb += bv[h * 64 + c] * wc;
            }
            w = s; bb = sb;
        } else {
            int jj = j - 384;
            float s = 0.f, sb = bc[jj];
            for (int c = 0; c < HD; c++) {
                float wc = Wc[c * DIM + jj];
                s  += Wskip[d * HD + c] * wc;
                sb += bskip[c] * wc;
            }
            w = s; bb = sb;
        }
        WallT[gid] = f2bf(w);
        if (d == 0) ball[j] = bb;
        return;
    }
    // ---- binning part ----
    __shared__ unsigned pk[ACH];        // 8 KB packed edges
    __shared__ unsigned char bbn[ACH];  // 2 KB bin ids (255 = invalid)
    __shared__ unsigned ord[ACH];       // 8 KB bin-ordered edges
    __shared__ int hist[256];
    __shared__ int lofs[256];
    __shared__ int gbase[256];
    const int e0 = (blockIdx.x - PREP_B) * ACH;
    hist[t] = 0;
    __syncthreads();
    for (int i = t; i < ACH; i += 256) {
        int e = e0 + i;
        if (e < N_EDGES) {
            int src = ei[e];
            int d = ei[N_EDGES + e];
            int bin = d >> 8;
            pk[i] = (unsigned)(((d & 255) << 16) | src);
            bbn[i] = (unsigned char)bin;
            atomicAdd(&hist[bin], 1);
        } else {
            bbn[i] = 255;
        }
    }
    __syncthreads();
    int h = hist[t];
    lofs[t] = h;
    __syncthreads();
    for (int off = 1; off < 256; off <<= 1) {
        int add = (t >= off) ? lofs[t - off] : 0;
        __syncthreads();
        lofs[t] += add;
        __syncthreads();
    }
    int excl = lofs[t] - h;
    if (t < NBIN && h > 0) gbase[t] = atomicAdd(&bincnt[t], h);
    __syncthreads();
    lofs[t] = excl;
    hist[t] = 0;
    __syncthreads();
    for (int i = t; i < ACH; i += 256) {
        int bin = bbn[i];
        if (bin != 255) {
            int sl = atomicAdd(&hist[bin], 1);
            ord[lofs[bin] + sl] = pk[i];
        }
    }
    __syncthreads();
    const int w = t >> 6, lane = t & 63;
    for (int bin = w; bin < NBIN; bin += 4) {
        int cnt = hist[bin];
        int lo = lofs[bin];
        int gb = gbase[bin];
        for (int i = lane; i < cnt; i += 64) {
            int pos = gb + i;
            if (pos < BCAP) bins[(size_t)bin * BCAP + pos] = ord[lo + i];
        }
    }
}

// ------- merged: MFMA projection GEMM ∥ bin->ELL (deg written directly) -------
__global__ __launch_bounds__(256) void k_ep(
    const float* __restrict__ x,
    const unsigned short* __restrict__ WallT, const float* __restrict__ ball,
    float* __restrict__ q, unsigned char* __restrict__ kv, float* __restrict__ skipc,
    const int* __restrict__ bincnt, const unsigned* __restrict__ bins,
    int* __restrict__ deg, unsigned short* __restrict__ elist)
{
    const int blk = blockIdx.x;
    const int t = threadIdx.x;
    if (blk >= PROJ_B) {
        const int bin = blk - PROJ_B;
        __shared__ int nodecnt[256];
        nodecnt[t] = 0;
        __syncthreads();
        int cnt = bincnt[bin]; if (cnt > BCAP) cnt = BCAP;
        const unsigned* bp = bins + (size_t)bin * BCAP;
        for (int i = t; i < cnt; i += 256) {
            unsigned p = bp[i];
            int local = p >> 16;
            int src = p & 0xffff;
            int sl = atomicAdd(&nodecnt[local], 1);
            if (sl < MAXDEG)
                elist[((size_t)((bin << 8) | local)) * MAXDEG + sl] = (unsigned short)src;
        }
        __syncthreads();
        int node = (bin << 8) + t;
        if (node < N_NODES) {
            int dgv = nodecnt[t];
            deg[node] = dgv > MAXDEG ? MAXDEG : dgv;
        }
        return;
    }
    const int w = t >> 6;
    const int lane = t & 63;
    const int col = lane & 31;
    const int khalf = lane >> 5;
    const int n0 = blk * 64 + (w >> 1) * 32;
    const int ct0 = (w & 1) * 7;
    const int rowbase = 4 * khalf;

    int nread = n0 + col; if (nread >= N_NODES) nread = N_NODES - 1;
    const float* ap = x + (size_t)nread * 64 + khalf * 8;
    bf16x8 afrag[4];
#pragma unroll
    for (int kk = 0; kk < 4; kk++) {
        float4 xa = *((const float4*)(ap + kk * 16));
        float4 xb4 = *((const float4*)(ap + kk * 16 + 4));
        bf16x8 f;
        f[0] = (short)f2bf(xa.x); f[1] = (short)f2bf(xa.y);
        f[2] = (short)f2bf(xa.z); f[3] = (short)f2bf(xa.w);
        f[4] = (short)f2bf(xb4.x); f[5] = (short)f2bf(xb4.y);
        f[6] = (short)f2bf(xb4.z); f[7] = (short)f2bf(xb4.w);
        afrag[kk] = f;
    }

    for (int tt = 0; tt < 7; tt++) {
        const int gc = (ct0 + tt) * 32 + col;
        const float b = ball[gc];
        f32x16 acc;
#pragma unroll
        for (int r = 0; r < 16; r++) acc[r] = b;
        const unsigned short* bp = WallT + (size_t)gc * 64 + khalf * 8;
#pragma unroll
        for (int kk = 0; kk < 4; kk++) {
            bf16x8 bfrag = *((const bf16x8*)(bp + kk * 16));
            acc = __builtin_amdgcn_mfma_f32_32x32x16_bf16(afrag[kk], bfrag, acc, 0, 0, 0);
        }
        if (gc < 128) {
#pragma unroll
            for (int r = 0; r < 16; r++) {
                int node = n0 + (r & 3) + 8 * (r >> 2) + rowbase;
                if (node < N_NODES) q[(size_t)node * HD + gc] = acc[r];
            }
        } else if (gc < 384) {
            int ch = gc - 128;
#pragma unroll
            for (int r = 0; r < 16; r++) {
                int node = n0 + (r & 3) + 8 * (r >> 2) + rowbase;
                if (node < N_NODES) kv[(size_t)node * 256 + ch] = f2fp8(acc[r]);
            }
        } else {
#pragma unroll
            for (int r = 0; r < 16; r++) {
                int node = n0 + (r & 3) + 8 * (r >> 2) + rowbase;
                if (node < N_NODES) skipc[(size_t)node * DIM + (gc - 384)] = acc[r];
            }
        }
    }
}

// -------- fused attention: fp8 kv gather, 8-edge-parallel softmax + skipc + stats ----
// 4 waves/block, one wave per dst node; 8 groups x 8 lanes.
// Unrolled 2x: 16 edges (2 batches) per loop iter -> 8 gather loads in flight/lane.
// All dot/acc math in f32x2 packed ops (v_pk_fma_f32); logits pre-scaled for exp2.
__global__ __launch_bounds__(256) void k_attn(
    const float* __restrict__ q, const unsigned char* __restrict__ kv,
    const float* __restrict__ skipc,
    const int* __restrict__ deg, const unsigned short* __restrict__ elist,
    float* __restrict__ out, float* __restrict__ parts)
{
    const int w = threadIdx.x >> 6;
    const int lane = threadIdx.x & 63;
    const int g = lane >> 3;   // edge group 0..7
    const int j = lane & 7;    // channels 8j..8j+7 of each head
    const int n = blockIdx.x * 4 + w;
    const f32x2* qp = (const f32x2*)(q + (size_t)n * HD);
    f32x2 q0[4], q1[4];
#pragma unroll
    for (int i = 0; i < 4; i++) { q0[i] = qp[4 * j + i]; q1[i] = qp[32 + 4 * j + i]; }
    const int myE = elist[(size_t)n * MAXDEG + lane];   // full ELL row, coalesced u16
    f32x2 acc0[4], acc1[4];
#pragma unroll
    for (int i = 0; i < 4; i++) {
        acc0[i] = (f32x2){0.f, 0.f};
        acc1[i] = (f32x2){0.f, 0.f};
    }
    float l0 = 0.f, l1 = 0.f;
    int dg = deg[n]; if (dg > MAXDEG) dg = MAXDEG;
    for (int b0 = 0; b0 < dg; b0 += 16) {
        int iA = b0 + g, iB = b0 + 8 + g;
        bool vA = iA < dg, vB = iB < dg;
        int sA = __shfl(myE, vA ? iA : 0, 64);
        int sB = __shfl(myE, vB ? iB : 0, 64);
        const uint2* kpA = (const uint2*)(kv + (size_t)sA * 256);
        const uint2* kpB = (const uint2*)(kv + (size_t)sB * 256);
        uint2 KA0 = kpA[j],      KA1 = kpA[8 + j];
        uint2 VA0 = kpA[16 + j], VA1 = kpA[24 + j];
        uint2 KB0 = kpB[j],      KB1 = kpB[8 + j];
        uint2 VB0 = kpB[16 + j], VB1 = kpB[24 + j];
        // ---- batch A logits (packed) ----
        f32x2 pa0 = q0[0] * __builtin_amdgcn_cvt_pk_f32_fp8(KA0.x, false);
        pa0 += q0[1] * __builtin_amdgcn_cvt_pk_f32_fp8(KA0.x, true);
        pa0 += q0[2] * __builtin_amdgcn_cvt_pk_f32_fp8(KA0.y, false);
        pa0 += q0[3] * __builtin_amdgcn_cvt_pk_f32_fp8(KA0.y, true);
        f32x2 pa1 = q1[0] * __builtin_amdgcn_cvt_pk_f32_fp8(KA1.x, false);
        pa1 += q1[1] * __builtin_amdgcn_cvt_pk_f32_fp8(KA1.x, true);
        pa1 += q1[2] * __builtin_amdgcn_cvt_pk_f32_fp8(KA1.y, false);
        pa1 += q1[3] * __builtin_amdgcn_cvt_pk_f32_fp8(KA1.y, true);
        float p0A = pa0[0] + pa0[1];
        float p1A = pa1[0] + pa1[1];
        // ---- batch B logits (packed) ----
        f32x2 pb0 = q0[0] * __builtin_amdgcn_cvt_pk_f32_fp8(KB0.x, false);
        pb0 += q0[1] * __builtin_amdgcn_cvt_pk_f32_fp8(KB0.x, true);
        pb0 += q0[2] * __builtin_amdgcn_cvt_pk_f32_fp8(KB0.y, false);
        pb0 += q0[3] * __builtin_amdgcn_cvt_pk_f32_fp8(KB0.y, true);
        f32x2 pb1 = q1[0] * __builtin_amdgcn_cvt_pk_f32_fp8(KB1.x, false);
        pb1 += q1[1] * __builtin_amdgcn_cvt_pk_f32_fp8(KB1.x, true);
        pb1 += q1[2] * __builtin_amdgcn_cvt_pk_f32_fp8(KB1.y, false);
        pb1 += q1[3] * __builtin_amdgcn_cvt_pk_f32_fp8(KB1.y, true);
        float p0B = pb0[0] + pb0[1];
        float p1B = pb1[0] + pb1[1];
        // ---- intra-group (8-lane) dot reduction, both batches together ----
#pragma unroll
        for (int off = 1; off < 8; off <<= 1) {
            p0A += __shfl_xor(p0A, off, 64);
            p1A += __shfl_xor(p1A, off, 64);
            p0B += __shfl_xor(p0B, off, 64);
            p1B += __shfl_xor(p1B, off, 64);
        }
        float w0A = vA ? __builtin_amdgcn_exp2f(p0A) : 0.f;
        float w1A = vA ? __builtin_amdgcn_exp2f(p1A) : 0.f;
        float w0B = vB ? __builtin_amdgcn_exp2f(p0B) : 0.f;
        float w1B = vB ? __builtin_amdgcn_exp2f(p1B) : 0.f;
        l0 += w0A + w0B; l1 += w1A + w1B;
        f32x2 w0Av = {w0A, w0A}, w1Av = {w1A, w1A};
        f32x2 w0Bv = {w0B, w0B}, w1Bv = {w1B, w1B};
        acc0[0] += w0Av * __builtin_amdgcn_cvt_pk_f32_fp8(VA0.x, false);
        acc0[1] += w0Av * __builtin_amdgcn_cvt_pk_f32_fp8(VA0.x, true);
        acc0[2] += w0Av * __builtin_amdgcn_cvt_pk_f32_fp8(VA0.y, false);
        acc0[3] += w0Av * __builtin_amdgcn_cvt_pk_f32_fp8(VA0.y, true);
        acc1[0] += w1Av * __builtin_amdgcn_cvt_pk_f32_fp8(VA1.x, false);
        acc1[1] += w1Av * __builtin_amdgcn_cvt_pk_f32_fp8(VA1.x, true);
        acc1[2] += w1Av * __builtin_amdgcn_cvt_pk_f32_fp8(VA1.y, false);
        acc1[3] += w1Av * __builtin_amdgcn_cvt_pk_f32_fp8(VA1.y, true);
        acc0[0] += w0Bv * __builtin_amdgcn_cvt_pk_f32_fp8(VB0.x, false);
        acc0[1] += w0Bv * __builtin_amdgcn_cvt_pk_f32_fp8(VB0.x, true);
        acc0[2] += w0Bv * __builtin_amdgcn_cvt_pk_f32_fp8(VB0.y, false);
        acc0[3] += w0Bv * __builtin_amdgcn_cvt_pk_f32_fp8(VB0.y, true);
        acc1[0] += w1Bv * __builtin_amdgcn_cvt_pk_f32_fp8(VB1.x, false);
        acc1[1] += w1Bv * __builtin_amdgcn_cvt_pk_f32_fp8(VB1.x, true);
        acc1[2] += w1Bv * __builtin_amdgcn_cvt_pk_f32_fp8(VB1.y, false);
        acc1[3] += w1Bv * __builtin_amdgcn_cvt_pk_f32_fp8(VB1.y, true);
    }
    // ---- cross-group reduction (once per node) ----
    float* a0 = (float*)acc0;
    float* a1 = (float*)acc1;
#pragma unroll
    for (int off = 8; off < 64; off <<= 1) {
        l0 += __shfl_xor(l0, off, 64);
        l1 += __shfl_xor(l1, off, 64);
#pragma unroll
        for (int i = 0; i < 8; i++) {
            a0[i] += __shfl_xor(a0[i], off, 64);
            a1[i] += __shfl_xor(a1[i], off, 64);
        }
    }
    if (g == 0) {
        float inv0 = 1.f / (l0 + 1e-16f), inv1 = 1.f / (l1 + 1e-16f);
        const float4* sk = (const float4*)(skipc + (size_t)n * DIM);
        float4 sa = sk[2 * j], sb = sk[2 * j + 1];
        float o[8];
        o[0] = a0[0] * inv0 + a1[0] * inv1 + sa.x;
        o[1] = a0[1] * inv0 + a1[1] * inv1 + sa.y;
        o[2] = a0[2] * inv0 + a1[2] * inv1 + sa.z;
        o[3] = a0[3] * inv0 + a1[3] * inv1 + sa.w;
        o[4] = a0[4] * inv0 + a1[4] * inv1 + sb.x;
        o[5] = a0[5] * inv0 + a1[5] * inv1 + sb.y;
        o[6] = a0[6] * inv0 + a1[6] * inv1 + sb.z;
        o[7] = a0[7] * inv0 + a1[7] * inv1 + sb.w;
        float4 r0 = {o[0], o[1], o[2], o[3]}, r1 = {o[4], o[5], o[6], o[7]};
        float4* op = (float4*)(out + (size_t)n * DIM);
        op[2 * j] = r0; op[2 * j + 1] = r1;
        float s_ = 0.f, ss = 0.f;
#pragma unroll
        for (int i = 0; i < 8; i++) { s_ += o[i]; ss += o[i] * o[i]; }
#pragma unroll
        for (int off = 1; off < 8; off <<= 1) {
            s_ += __shfl_xor(s_, off, 64);
            ss += __shfl_xor(ss, off, 64);
        }
        if (j == 0) { parts[n] = s_; parts[N_NODES + n] = ss; }
    }
}

// ---------------- multi-block reduction of parts -> stats (f64 atomics) ----------
#define RED_BLOCKS 100
__global__ __launch_bounds__(256) void k_reduce(
    const float* __restrict__ parts, double* __restrict__ stats)
{
    double s = 0.0, ss = 0.0;
    for (int i = blockIdx.x * 256 + threadIdx.x; i < N_NODES; i += RED_BLOCKS * 256) {
        s  += (double)parts[i];
        ss += (double)parts[N_NODES + i];
    }
#pragma unroll
    for (int off = 32; off > 0; off >>= 1) {
        s  += __shfl_down(s, off);
        ss += __shfl_down(ss, off);
    }
    __shared__ double sdd[8];
    int wave = threadIdx.x >> 6;
    if ((threadIdx.x & 63) == 0) { sdd[wave * 2] = s; sdd[wave * 2 + 1] = ss; }
    __syncthreads();
    if (threadIdx.x == 0) {
        double S = 0.0, SS = 0.0;
        for (int w = 0; w < 4; w++) { S += sdd[w * 2]; SS += sdd[w * 2 + 1]; }
        atomicAdd(&stats[0], S);
        atomicAdd(&stats[1], SS);
    }
}

// ---------------- graph layernorm + gamma/beta (in-place on d_out, float4) --------
__global__ __launch_bounds__(256) void k_norm(
    float* __restrict__ out, const double* __restrict__ stats,
    const float* __restrict__ gamma, const float* __restrict__ beta)
{
    int i = blockIdx.x * 256 + threadIdx.x;
    if (i >= N_NODES * DIM / 4) return;
    const double cnt = (double)N_NODES * (double)DIM;
    double mean = stats[0] / cnt;
    double var  = stats[1] / cnt - mean * mean;
    if (var < 0.0) var = 0.0;
    float mf = (float)mean;
    float inv = 1.0f / ((float)sqrt(var) + 1e-5f);
    float4 v = ((const float4*)out)[i];
    float4 gv = ((const float4*)gamma)[i & 15];
    float4 bv2 = ((const float4*)beta)[i & 15];
    v.x = (v.x - mf) * inv * gv.x + bv2.x;
    v.y = (v.y - mf) * inv * gv.y + bv2.y;
    v.z = (v.z - mf) * inv * gv.z + bv2.z;
    v.w = (v.w - mf) * inv * gv.w + bv2.w;
    ((float4*)out)[i] = v;
}

extern "C" void kernel_launch(void* const* d_in, const int* in_sizes, int n_in,
                              void* d_out, int out_size, void* d_ws, size_t ws_size,
                              hipStream_t stream) {
    const float* x     = (const float*)d_in[0];
    const int*   ei    = (const int*)d_in[1];
    const float* Wq    = (const float*)d_in[2];
    const float* bq    = (const float*)d_in[3];
    const float* Wk    = (const float*)d_in[4];
    const float* bk    = (const float*)d_in[5];
    const float* Wv    = (const float*)d_in[6];
    const float* bv    = (const float*)d_in[7];
    const float* Wsk   = (const float*)d_in[8];
    const float* bsk   = (const float*)d_in[9];
    const float* Wc    = (const float*)d_in[10];
    const float* bc    = (const float*)d_in[11];
    const float* gamma = (const float*)d_in[12];
    const float* beta  = (const float*)d_in[13];
    float* out = (float*)d_out;

    // ws layout
    float* ws = (float*)d_ws;
    const size_t NF = (size_t)N_NODES * HD;               // 6.4M floats
    float* q = ws;                                        // [N,128] f32
    unsigned char* kv = (unsigned char*)(ws + NF);        // [N,256] fp8 (k|vc)
    float* skipc = (float*)(kv + (size_t)N_NODES * 256);  // [N,64]  f32
    unsigned short* WallT = (unsigned short*)(skipc + (size_t)N_NODES * DIM); // [448,64]
    float* ball   = (float*)(WallT + NCOL * 64);          // [448]
    int* bincnt   = (int*)(ball + NCOL);                  // [NBIN]
    unsigned* bins = (unsigned*)(bincnt + 256);           // [NBIN*BCAP] packed edges
    int* deg      = (int*)(bins + (size_t)NBIN * BCAP);   // [N]
    unsigned short* elist = (unsigned short*)(deg + N_NODES); // [NBIN*256*64] u16 ELL
    float* parts  = (float*)(elist + (size_t)NBIN * 256 * MAXDEG); // [2,N] split
    double* stats = (double*)(parts + (size_t)N_NODES * 2);

    hipMemsetAsync(bincnt, 0, NBIN * sizeof(int), stream);
    hipLaunchKernelGGL(k_pb, dim3(PREP_B + BIN_BLKS), dim3(256), 0, stream,
                       ei, Wq, bq, Wk, bk, Wv, bv, Wsk, bsk, Wc, bc,
                       WallT, ball, bincnt, bins, stats);
    hipLaunchKernelGGL(k_ep, dim3(PROJ_B + NBIN), dim3(256), 0, stream,
                       x, WallT, ball, q, kv, skipc, bincnt, bins, deg, elist);
    hipLaunchKernelGGL(k_attn, dim3(N_NODES / 4), dim3(256), 0, stream,
                       q, kv, skipc, deg, elist, out, parts);
    hipLaunchKernelGGL(k_reduce, dim3(RED_BLOCKS), dim3(256), 0, stream, parts, stats);
    hipLaunchKernelGGL(k_norm, dim3(N_NODES * DIM / 4 / 256 + 1), dim3(256), 0, stream,
                       out, stats, gamma, beta);
}